// Round 8
// baseline (2571.207 us; speedup 1.0000x reference)
//
#include <hip/hip_runtime.h>
#include <stdint.h>

#define NB 4
#define NN 8192
#define KNB 30
#define TOT (NB * NN)

// ---------------- threefry2x32 (JAX-exact, key = [0, 42]) ----------------
__device__ __forceinline__ uint32_t rotl32(uint32_t v, int r) {
    return (v << r) | (v >> (32 - r));
}

__device__ __forceinline__ void threefry(uint32_t x0, uint32_t x1,
                                         uint32_t& o0, uint32_t& o1) {
    const uint32_t ks0 = 0u, ks1 = 42u, ks2 = 0u ^ 42u ^ 0x1BD11BDAu;
    x0 += ks0; x1 += ks1;
#define RND(r) { x0 += x1; x1 = rotl32(x1, r); x1 ^= x0; }
    RND(13) RND(15) RND(26) RND(6)
    x0 += ks1; x1 += ks2 + 1u;
    RND(17) RND(29) RND(16) RND(24)
    x0 += ks2; x1 += ks0 + 2u;
    RND(13) RND(15) RND(26) RND(6)
    x0 += ks0; x1 += ks1 + 3u;
    RND(17) RND(29) RND(16) RND(24)
    x0 += ks1; x1 += ks2 + 4u;
    RND(13) RND(15) RND(26) RND(6)
    x0 += ks2; x1 += ks0 + 5u;
#undef RND
    o0 = x0; o1 = x1;
}

// jax_threefry_partitionable=True: bits[t] = o0^o1 of threefry(key, 0, t)
__global__ void init_z_kernel(float* __restrict__ z) {
    int t = blockIdx.x * blockDim.x + threadIdx.x;
    if (t >= TOT) return;
    uint32_t o0, o1;
    threefry(0u, (uint32_t)t, o0, o1);
    uint32_t bits = o0 ^ o1;
    z[t] = __uint_as_float((bits >> 9) | 0x3f800000u) - 1.0f;
}

// ---------------- kNN: block per row; wave-local top-30, then merge ----------
// R4-proven pieces: d[32] cached (j = s*256 + t), cm[4] chunk minima, MKKEY,
// two-phase wave reduce, value-match winner rescan of CACHED registers.
// New: per-wave top-30 into LDS (no barriers in loop), one barrier, threshold
// merge of 120 candidates. Keys (d2_bits<<32)|j are unique; low-j tie-break
// matches lax.top_k.
__global__ __launch_bounds__(256) void knn_kernel(const float* __restrict__ X,
                                                  const int* __restrict__ C,
                                                  int* __restrict__ edges) {
    const int row = blockIdx.x;          // 0..TOT-1 (block per row, as R4)
    const int b = row >> 13;
    const int i = row & (NN - 1);
    const float* Xb = X + (size_t)b * NN * 3;
    const int* Cb = C + (size_t)b * NN;
    const float xi = Xb[i * 3 + 0], yi = Xb[i * 3 + 1], zi = Xb[i * 3 + 2];
    const int t = threadIdx.x;
    const int w = t >> 6;                // wave id (4 waves)

    // d2 for j = s*256 + t, exact reference op order — VERBATIM R4
    float d[32];
#pragma unroll
    for (int s = 0; s < 32; ++s) {
        int j = s * 256 + t;
        float dx = __fsub_rn(xi, Xb[j * 3 + 0]);
        float dy = __fsub_rn(yi, Xb[j * 3 + 1]);
        float dz = __fsub_rn(zi, Xb[j * 3 + 2]);
        float d2 = __fadd_rn(__fadd_rn(__fmul_rn(dx, dx), __fmul_rn(dy, dy)),
                             __fmul_rn(dz, dz));
        d2 = __fadd_rn(d2, (Cb[j] > 0) ? 0.0f : 1e9f);
        d2 = __fadd_rn(d2, (j == i) ? 1e9f : 0.0f);
        d[s] = d2;
    }

#define MKKEY(s) ((((unsigned long long)__float_as_uint(d[(s)])) << 32) | \
                  (unsigned)((s) * 256 + t))

    // per-chunk minima (chunks of 8) — VERBATIM R4
    unsigned long long cm[4];
#pragma unroll
    for (int c = 0; c < 4; ++c) {
        unsigned long long m = ~0ull;
#pragma unroll
        for (int s8 = 0; s8 < 8; ++s8) {
            unsigned long long key = MKKEY(c * 8 + s8);
            m = key < m ? key : m;
        }
        cm[c] = m;
    }
    unsigned long long lb =
        (cm[0] < cm[1] ? cm[0] : cm[1]) < (cm[2] < cm[3] ? cm[2] : cm[3])
            ? (cm[0] < cm[1] ? cm[0] : cm[1])
            : (cm[2] < cm[3] ? cm[2] : cm[3]);

    __shared__ unsigned long long lds_cand[4 * KNB];  // 120 keys

    // Phase 1: each wave selects ITS top-30 (of its 2048 keys), barrier-free.
    for (int kk = 0; kk < KNB; ++kk) {
        // two-phase wave reduce — VERBATIM R4
        uint32_t hi = (uint32_t)(lb >> 32);
        uint32_t lo = (uint32_t)lb;
        uint32_t m = hi;
#pragma unroll
        for (int off = 32; off >= 1; off >>= 1) {
            uint32_t o = __shfl_xor(m, off, 64);
            m = o < m ? o : m;
        }
        uint32_t cand = (hi == m) ? lo : 0xFFFFFFFFu;
#pragma unroll
        for (int off = 32; off >= 1; off >>= 1) {
            uint32_t o = __shfl_xor(cand, off, 64);
            cand = o < cand ? o : cand;
        }
        unsigned long long g = (((unsigned long long)m) << 32) | cand;
        if ((t & 63) == 0) lds_cand[w * KNB + kk] = g;

        if (lb == g) {
            // winner thread: rescan chunks whose cached min equals g — VERBATIM R4
#pragma unroll
            for (int c = 0; c < 4; ++c) {
                if (cm[c] == g) {
                    unsigned long long m2 = ~0ull;
#pragma unroll
                    for (int s8 = 0; s8 < 8; ++s8) {
                        unsigned long long key = MKKEY(c * 8 + s8);
                        if (key > g && key < m2) m2 = key;
                    }
                    cm[c] = m2;
                }
            }
            unsigned long long a0 = cm[0] < cm[1] ? cm[0] : cm[1];
            unsigned long long a1 = cm[2] < cm[3] ? cm[2] : cm[3];
            lb = a0 < a1 ? a0 : a1;
        }
    }
#undef MKKEY

    __syncthreads();  // all 120 wave-local candidates visible

    // Phase 2: merge 120 candidates -> global top-30 (all waves redundantly).
    const int l = t & 63;
    unsigned long long k0 = lds_cand[l];                       // l < 64 < 120
    unsigned long long k1 = (l + 64 < 4 * KNB) ? lds_cand[l + 64] : ~0ull;
    unsigned long long prev = 0ull;
    for (int kk = 0; kk < KNB; ++kk) {
        unsigned long long a = (kk == 0 || k0 > prev) ? k0 : ~0ull;
        unsigned long long c2 = (kk == 0 || k1 > prev) ? k1 : ~0ull;
        unsigned long long mlb = a < c2 ? a : c2;

        uint32_t hi = (uint32_t)(mlb >> 32);
        uint32_t lo = (uint32_t)mlb;
        uint32_t m = hi;
#pragma unroll
        for (int off = 32; off >= 1; off >>= 1) {
            uint32_t o = __shfl_xor(m, off, 64);
            m = o < m ? o : m;
        }
        uint32_t cand = (hi == m) ? lo : 0xFFFFFFFFu;
#pragma unroll
        for (int off = 32; off >= 1; off >>= 1) {
            uint32_t o = __shfl_xor(cand, off, 64);
            cand = o < cand ? o : cand;
        }
        unsigned long long g = (((unsigned long long)m) << 32) | cand;
        if (t == 0) edges[(size_t)row * KNB + kk] = (int)cand;
        prev = g;
    }
}

// ---------------- one smoothing step (all selected neighbors are valid) -------
__global__ void smooth_kernel(const float* __restrict__ zin,
                              float* __restrict__ zout,
                              const int* __restrict__ edges,
                              const int* __restrict__ C) {
    int t = blockIdx.x * blockDim.x + threadIdx.x;
    if (t >= TOT) return;
    float acc = 0.0f;
    if (C[t] > 0) {
        const int b = t >> 13;
        const int* e = edges + (size_t)t * KNB;
        const float* zb = zin + (size_t)b * NN;
#pragma unroll
        for (int k = 0; k < KNB; ++k) acc = __fadd_rn(acc, zb[e[k]]);
        acc = __fdiv_rn(acc, __fadd_rn(30.0f, 1e-5f));
    }
    zout[t] = acc;
}

// ---------------- z += priority; stable ascending argsort per batch ----------
__global__ __launch_bounds__(1024) void sort_kernel(const float* __restrict__ z,
                                                    const float* __restrict__ prio,
                                                    int* __restrict__ out) {
    __shared__ unsigned long long keys[NN];  // 64 KiB
    const int b = blockIdx.x;
    for (int i = threadIdx.x; i < NN; i += 1024) {
        float v = z[(size_t)b * NN + i] + prio[(size_t)b * NN + i];
        uint32_t u = __float_as_uint(v);
        u ^= (u >> 31) ? 0xFFFFFFFFu : 0x80000000u;  // monotonic float->uint
        keys[i] = ((unsigned long long)u << 32) | (unsigned)i;
    }
    __syncthreads();
    for (int k = 2; k <= NN; k <<= 1) {
        for (int j = k >> 1; j > 0; j >>= 1) {
            for (int i = threadIdx.x; i < NN; i += 1024) {
                int ixj = i ^ j;
                if (ixj > i) {
                    unsigned long long a = keys[i], c = keys[ixj];
                    bool up = ((i & k) == 0);
                    if ((a > c) == up) { keys[i] = c; keys[ixj] = a; }
                }
            }
            __syncthreads();
        }
    }
    for (int i = threadIdx.x; i < NN; i += 1024)
        out[(size_t)b * NN + i] = (int)(keys[i] & 0xffffffffu);
}

extern "C" void kernel_launch(void* const* d_in, const int* in_sizes, int n_in,
                              void* d_out, int out_size, void* d_ws, size_t ws_size,
                              hipStream_t stream) {
    const float* X = (const float*)d_in[0];    // [4,8192,3] f32
    const int* C = (const int*)d_in[1];        // [4,8192] int32
    const float* prio = (const float*)d_in[2]; // [4,8192] f32
    int* out = (int*)d_out;                    // [4,8192] i32

    float* z0 = (float*)d_ws;
    float* z1 = z0 + TOT;
    int* edges = (int*)(z1 + TOT);

    init_z_kernel<<<TOT / 256, 256, 0, stream>>>(z0);
    knn_kernel<<<TOT, 256, 0, stream>>>(X, C, edges);

    float* cur = z0;
    float* nxt = z1;
    for (int s = 0; s < 5; ++s) {
        smooth_kernel<<<TOT / 256, 256, 0, stream>>>(cur, nxt, edges, C);
        float* tmp = cur; cur = nxt; nxt = tmp;
    }
    sort_kernel<<<NB, 1024, 0, stream>>>(cur, prio, out);
}

// Round 9
// 770.114 us; speedup vs baseline: 3.3387x; 3.3387x over previous
//
#include <hip/hip_runtime.h>
#include <stdint.h>

#define NB 4
#define NN 8192
#define KNB 30
#define TOT (NB * NN)

// ---------------- threefry2x32 (JAX-exact, key = [0, 42]) ----------------
__device__ __forceinline__ uint32_t rotl32(uint32_t v, int r) {
    return (v << r) | (v >> (32 - r));
}

__device__ __forceinline__ void threefry(uint32_t x0, uint32_t x1,
                                         uint32_t& o0, uint32_t& o1) {
    const uint32_t ks0 = 0u, ks1 = 42u, ks2 = 0u ^ 42u ^ 0x1BD11BDAu;
    x0 += ks0; x1 += ks1;
#define RND(r) { x0 += x1; x1 = rotl32(x1, r); x1 ^= x0; }
    RND(13) RND(15) RND(26) RND(6)
    x0 += ks1; x1 += ks2 + 1u;
    RND(17) RND(29) RND(16) RND(24)
    x0 += ks2; x1 += ks0 + 2u;
    RND(13) RND(15) RND(26) RND(6)
    x0 += ks0; x1 += ks1 + 3u;
    RND(17) RND(29) RND(16) RND(24)
    x0 += ks1; x1 += ks2 + 4u;
    RND(13) RND(15) RND(26) RND(6)
    x0 += ks2; x1 += ks0 + 5u;
#undef RND
    o0 = x0; o1 = x1;
}

// jax_threefry_partitionable=True: bits[t] = o0^o1 of threefry(key, 0, t)
__global__ void init_z_kernel(float* __restrict__ z) {
    int t = blockIdx.x * blockDim.x + threadIdx.x;
    if (t >= TOT) return;
    uint32_t o0, o1;
    threefry(0u, (uint32_t)t, o0, o1);
    uint32_t bits = o0 ^ o1;
    z[t] = __uint_as_float((bits >> 9) | 0x3f800000u) - 1.0f;
}

// ---------------- kNN via radix-select (no serial extraction rounds) ---------
// Keys: (d2_bits << 32) | j. d2 >= 0 -> float bits monotonic as uint; keys
// unique (j); ascending (d2bits, j) order == lax.top_k order incl. tie-break.
// 4 x 8-bit radix levels on d2bits find V = d2bits of the 30th-smallest key;
// collect all keys with d2bits <= V (<= 29 strictly-less, + ties); wave 0
// bitonic-sorts <=64 of them; first 30 = exact answer in order.
__global__ __launch_bounds__(256) void knn_kernel(const float* __restrict__ X,
                                                  const int* __restrict__ C,
                                                  int* __restrict__ edges) {
    const int row = blockIdx.x;          // 0..TOT-1 (block per row)
    const int b = row >> 13;
    const int i = row & (NN - 1);
    const float* Xb = X + (size_t)b * NN * 3;
    const int* Cb = C + (size_t)b * NN;
    const float xi = Xb[i * 3 + 0], yi = Xb[i * 3 + 1], zi = Xb[i * 3 + 2];
    const int t = threadIdx.x;

    // d2 for j = s*256 + t, exact reference op order — VERBATIM R4 (proven)
    float d[32];
#pragma unroll
    for (int s = 0; s < 32; ++s) {
        int j = s * 256 + t;
        float dx = __fsub_rn(xi, Xb[j * 3 + 0]);
        float dy = __fsub_rn(yi, Xb[j * 3 + 1]);
        float dz = __fsub_rn(zi, Xb[j * 3 + 2]);
        float d2 = __fadd_rn(__fadd_rn(__fmul_rn(dx, dx), __fmul_rn(dy, dy)),
                             __fmul_rn(dz, dz));
        d2 = __fadd_rn(d2, (Cb[j] > 0) ? 0.0f : 1e9f);
        d2 = __fadd_rn(d2, (j == i) ? 1e9f : 0.0f);
        d[s] = d2;
    }

#define MKKEY(s) ((((unsigned long long)__float_as_uint(d[(s)])) << 32) | \
                  (unsigned)((s) * 256 + t))

    __shared__ uint32_t hist[16][257];     // 16 sub-hists, +1 pad breaks bank alias
    __shared__ uint32_t sel2[2];           // [0]=value prefix, [1]=remaining rank
    __shared__ unsigned long long cbuf[64];
    __shared__ uint32_t ccnt;

    const int sh = t >> 4;                 // sub-histogram id (16 threads each)

#pragma unroll
    for (int L = 0; L < 4; ++L) {
        const int shift = 24 - 8 * L;
        const uint32_t pmask = (L == 0) ? 0u : (0xFFFFFFFFu << (32 - 8 * L));
        // zero histograms (thread t zeroes column t of every sub-hist)
#pragma unroll
        for (int q = 0; q < 16; ++q) hist[q][t] = 0u;
        if (L == 0 && t == 0) { sel2[0] = 0u; sel2[1] = (uint32_t)KNB; ccnt = 0u; }
        __syncthreads();
        const uint32_t pref = sel2[0];
        // count keys matching current prefix into this thread-group's sub-hist
#pragma unroll
        for (int s = 0; s < 32; ++s) {
            uint32_t hb = __float_as_uint(d[s]);
            if ((hb & pmask) == pref)
                atomicAdd(&hist[sh][(hb >> shift) & 255], 1u);
        }
        __syncthreads();
        // reduce 16 sub-hists into hist[0][t] (each thread owns one column)
        uint32_t colsum = 0;
#pragma unroll
        for (int q = 0; q < 16; ++q) colsum += hist[q][t];
        hist[0][t] = colsum;
        __syncthreads();
        // wave 0: find bucket containing remaining rank r (1-indexed)
        if (t < 64) {
            uint32_t c0 = hist[0][4 * t + 0], c1 = hist[0][4 * t + 1];
            uint32_t c2 = hist[0][4 * t + 2], c3 = hist[0][4 * t + 3];
            uint32_t lsum = c0 + c1 + c2 + c3;
            uint32_t inc = lsum;
#pragma unroll
            for (int off = 1; off < 64; off <<= 1) {
                uint32_t o = __shfl_up(inc, off, 64);
                if (t >= off) inc += o;
            }
            uint32_t exc = inc - lsum;
            uint32_t r = sel2[1];
            if (exc < r && r <= inc) {     // exactly one lane brackets r
                uint32_t e = exc, bkt;
                if (r <= e + c0)                { bkt = 4u * t + 0u; }
                else if (r <= e + c0 + c1)      { bkt = 4u * t + 1u; e += c0; }
                else if (r <= e + c0 + c1 + c2) { bkt = 4u * t + 2u; e += c0 + c1; }
                else                            { bkt = 4u * t + 3u; e += c0 + c1 + c2; }
                sel2[0] = pref | (bkt << shift);
                sel2[1] = r - e;
            }
        }
        __syncthreads();
    }

    const uint32_t V = sel2[0];  // exact d2bits of the 30th-smallest key
    // collect all keys with d2bits <= V (n >= 30 by rank definition)
#pragma unroll
    for (int s = 0; s < 32; ++s) {
        uint32_t hb = __float_as_uint(d[s]);
        if (hb <= V) {
            uint32_t p = atomicAdd(&ccnt, 1u);
            if (p < 64u) cbuf[p] = MKKEY(s);
        }
    }
#undef MKKEY
    __syncthreads();
    const uint32_t n = ccnt < 64u ? ccnt : 64u;
    // wave 0: bitonic sort 64 (same network as proven sort_kernel, via shfl)
    if (t < 64) {
        unsigned long long key = ((uint32_t)t < n) ? cbuf[t] : ~0ull;
#pragma unroll
        for (int k = 2; k <= 64; k <<= 1) {
            for (int j2 = k >> 1; j2 > 0; j2 >>= 1) {
                unsigned long long o = __shfl_xor(key, j2, 64);
                bool up = ((t & k) == 0);
                bool lower = ((t & j2) == 0);
                unsigned long long mn = key < o ? key : o;
                unsigned long long mx = key < o ? o : key;
                key = (up == lower) ? mn : mx;
            }
        }
        if (t < KNB) edges[(size_t)row * KNB + t] = (int)(key & 0xffffffffu);
    }
}

// ---------------- one smoothing step (all selected neighbors are valid) -------
__global__ void smooth_kernel(const float* __restrict__ zin,
                              float* __restrict__ zout,
                              const int* __restrict__ edges,
                              const int* __restrict__ C) {
    int t = blockIdx.x * blockDim.x + threadIdx.x;
    if (t >= TOT) return;
    float acc = 0.0f;
    if (C[t] > 0) {
        const int b = t >> 13;
        const int* e = edges + (size_t)t * KNB;
        const float* zb = zin + (size_t)b * NN;
#pragma unroll
        for (int k = 0; k < KNB; ++k) acc = __fadd_rn(acc, zb[e[k]]);
        acc = __fdiv_rn(acc, __fadd_rn(30.0f, 1e-5f));
    }
    zout[t] = acc;
}

// ---------------- z += priority; stable ascending argsort per batch ----------
__global__ __launch_bounds__(1024) void sort_kernel(const float* __restrict__ z,
                                                    const float* __restrict__ prio,
                                                    int* __restrict__ out) {
    __shared__ unsigned long long keys[NN];  // 64 KiB
    const int b = blockIdx.x;
    for (int i = threadIdx.x; i < NN; i += 1024) {
        float v = z[(size_t)b * NN + i] + prio[(size_t)b * NN + i];
        uint32_t u = __float_as_uint(v);
        u ^= (u >> 31) ? 0xFFFFFFFFu : 0x80000000u;  // monotonic float->uint
        keys[i] = ((unsigned long long)u << 32) | (unsigned)i;
    }
    __syncthreads();
    for (int k = 2; k <= NN; k <<= 1) {
        for (int j = k >> 1; j > 0; j >>= 1) {
            for (int i = threadIdx.x; i < NN; i += 1024) {
                int ixj = i ^ j;
                if (ixj > i) {
                    unsigned long long a = keys[i], c = keys[ixj];
                    bool up = ((i & k) == 0);
                    if ((a > c) == up) { keys[i] = c; keys[ixj] = a; }
                }
            }
            __syncthreads();
        }
    }
    for (int i = threadIdx.x; i < NN; i += 1024)
        out[(size_t)b * NN + i] = (int)(keys[i] & 0xffffffffu);
}

extern "C" void kernel_launch(void* const* d_in, const int* in_sizes, int n_in,
                              void* d_out, int out_size, void* d_ws, size_t ws_size,
                              hipStream_t stream) {
    const float* X = (const float*)d_in[0];    // [4,8192,3] f32
    const int* C = (const int*)d_in[1];        // [4,8192] int32
    const float* prio = (const float*)d_in[2]; // [4,8192] f32
    int* out = (int*)d_out;                    // [4,8192] i32

    float* z0 = (float*)d_ws;
    float* z1 = z0 + TOT;
    int* edges = (int*)(z1 + TOT);

    init_z_kernel<<<TOT / 256, 256, 0, stream>>>(z0);
    knn_kernel<<<TOT, 256, 0, stream>>>(X, C, edges);

    float* cur = z0;
    float* nxt = z1;
    for (int s = 0; s < 5; ++s) {
        smooth_kernel<<<TOT / 256, 256, 0, stream>>>(cur, nxt, edges, C);
        float* tmp = cur; cur = nxt; nxt = tmp;
    }
    sort_kernel<<<NB, 1024, 0, stream>>>(cur, prio, out);
}

// Round 10
// 610.311 us; speedup vs baseline: 4.2129x; 1.2618x over previous
//
#include <hip/hip_runtime.h>
#include <stdint.h>

#define NB 4
#define NN 8192
#define KNB 30
#define TOT (NB * NN)

// ---------------- threefry2x32 (JAX-exact, key = [0, 42]) ----------------
__device__ __forceinline__ uint32_t rotl32(uint32_t v, int r) {
    return (v << r) | (v >> (32 - r));
}

__device__ __forceinline__ void threefry(uint32_t x0, uint32_t x1,
                                         uint32_t& o0, uint32_t& o1) {
    const uint32_t ks0 = 0u, ks1 = 42u, ks2 = 0u ^ 42u ^ 0x1BD11BDAu;
    x0 += ks0; x1 += ks1;
#define RND(r) { x0 += x1; x1 = rotl32(x1, r); x1 ^= x0; }
    RND(13) RND(15) RND(26) RND(6)
    x0 += ks1; x1 += ks2 + 1u;
    RND(17) RND(29) RND(16) RND(24)
    x0 += ks2; x1 += ks0 + 2u;
    RND(13) RND(15) RND(26) RND(6)
    x0 += ks0; x1 += ks1 + 3u;
    RND(17) RND(29) RND(16) RND(24)
    x0 += ks1; x1 += ks2 + 4u;
    RND(13) RND(15) RND(26) RND(6)
    x0 += ks2; x1 += ks0 + 5u;
#undef RND
    o0 = x0; o1 = x1;
}

// jax_threefry_partitionable=True: bits[t] = o0^o1 of threefry(key, 0, t)
__global__ void init_z_kernel(float* __restrict__ z) {
    int t = blockIdx.x * blockDim.x + threadIdx.x;
    if (t >= TOT) return;
    uint32_t o0, o1;
    threefry(0u, (uint32_t)t, o0, o1);
    uint32_t bits = o0 ^ o1;
    z[t] = __uint_as_float((bits >> 9) | 0x3f800000u) - 1.0f;
}

// ---------------- kNN via radix-select with early exit -----------------------
// Keys: (d2_bits << 32) | j. d2 >= 0 -> float bits monotonic as uint; keys
// unique (j); ascending (d2bits, j) == lax.top_k order incl. tie-break.
// 8-bit radix levels refine the value prefix of the 30th-smallest d2. We may
// stop at ANY level where collected count (30 - r_new) + cB <= 64: collect all
// keys with hb <= prefix|bucket|0xFF.. and bitonic-sort; first 30 are exact.
// Fallthrough after level 3 == R9-proven exact path.
__global__ __launch_bounds__(256) void knn_kernel(const float* __restrict__ X,
                                                  const int* __restrict__ C,
                                                  int* __restrict__ edges) {
    const int row = blockIdx.x;          // 0..TOT-1 (block per row)
    const int b = row >> 13;
    const int i = row & (NN - 1);
    const float* Xb = X + (size_t)b * NN * 3;
    const int* Cb = C + (size_t)b * NN;
    const float xi = Xb[i * 3 + 0], yi = Xb[i * 3 + 1], zi = Xb[i * 3 + 2];
    const int t = threadIdx.x;

    // d2 for j = s*256 + t, exact reference op order — VERBATIM R4 (proven)
    float d[32];
#pragma unroll
    for (int s = 0; s < 32; ++s) {
        int j = s * 256 + t;
        float dx = __fsub_rn(xi, Xb[j * 3 + 0]);
        float dy = __fsub_rn(yi, Xb[j * 3 + 1]);
        float dz = __fsub_rn(zi, Xb[j * 3 + 2]);
        float d2 = __fadd_rn(__fadd_rn(__fmul_rn(dx, dx), __fmul_rn(dy, dy)),
                             __fmul_rn(dz, dz));
        d2 = __fadd_rn(d2, (Cb[j] > 0) ? 0.0f : 1e9f);
        d2 = __fadd_rn(d2, (j == i) ? 1e9f : 0.0f);
        d[s] = d2;
    }

#define MKKEY(s) ((((unsigned long long)__float_as_uint(d[(s)])) << 32) | \
                  (unsigned)((s) * 256 + t))

    __shared__ uint32_t hist[16][257];   // 16 sub-hists, +1 pad breaks bank alias
    __shared__ uint32_t sel3[3];         // [0]=prefix, [1]=remaining rank, [2]=cB
    __shared__ unsigned long long cbuf[64];
    __shared__ uint32_t ccnt;

    const int sh = t >> 4;               // sub-histogram id (16 threads each)
    if (t == 0) { sel3[0] = 0u; sel3[1] = (uint32_t)KNB; sel3[2] = 0u; ccnt = 0u; }

    int exitShift = 0;                   // shift of the level we stopped at
    for (int L = 0; L < 4; ++L) {
        const int shift = 24 - 8 * L;
        const uint32_t pmask = (L == 0) ? 0u : (0xFFFFFFFFu << (32 - 8 * L));
        // zero histograms (thread t zeroes column t of every sub-hist)
        for (int q = 0; q < 16; ++q) hist[q][t] = 0u;
        __syncthreads();                 // also publishes sel3/ccnt init (L=0)
        const uint32_t pref = sel3[0];
        // count keys matching current prefix into this thread-group's sub-hist
#pragma unroll
        for (int s = 0; s < 32; ++s) {
            uint32_t hb = __float_as_uint(d[s]);
            if ((hb & pmask) == pref)
                atomicAdd(&hist[sh][(hb >> shift) & 255], 1u);
        }
        __syncthreads();
        // reduce 16 sub-hists into hist[0][t]
        uint32_t colsum = 0;
#pragma unroll
        for (int q = 0; q < 16; ++q) colsum += hist[q][t];
        hist[0][t] = colsum;
        __syncthreads();
        // wave 0: find bucket containing remaining rank r (1-indexed)
        if (t < 64) {
            uint32_t c0 = hist[0][4 * t + 0], c1 = hist[0][4 * t + 1];
            uint32_t c2 = hist[0][4 * t + 2], c3 = hist[0][4 * t + 3];
            uint32_t lsum = c0 + c1 + c2 + c3;
            uint32_t inc = lsum;
#pragma unroll
            for (int off = 1; off < 64; off <<= 1) {
                uint32_t o = __shfl_up(inc, off, 64);
                if (t >= off) inc += o;
            }
            uint32_t exc = inc - lsum;
            uint32_t r = sel3[1];
            if (exc < r && r <= inc) {   // exactly one lane brackets r
                uint32_t e = exc, bkt, cB;
                if (r <= e + c0)                { bkt = 4u * t + 0u; cB = c0; }
                else if (r <= e + c0 + c1)      { bkt = 4u * t + 1u; cB = c1; e += c0; }
                else if (r <= e + c0 + c1 + c2) { bkt = 4u * t + 2u; cB = c2; e += c0 + c1; }
                else                            { bkt = 4u * t + 3u; cB = c3; e += c0 + c1 + c2; }
                sel3[0] = pref | (bkt << shift);
                sel3[1] = r - e;         // rank within chosen bucket
                sel3[2] = cB;            // bucket population
            }
        }
        __syncthreads();
        // uniform early exit: collected set (below-prefix + bucket) fits cbuf
        if ((uint32_t)KNB - sel3[1] + sel3[2] <= 64u) { exitShift = shift; break; }
    }

    const uint32_t V = sel3[0] | ((exitShift > 0) ? ((1u << exitShift) - 1u) : 0u);
    // collect all keys with d2bits <= V (30 <= n <= 64 on early exit)
#pragma unroll
    for (int s = 0; s < 32; ++s) {
        uint32_t hb = __float_as_uint(d[s]);
        if (hb <= V) {
            uint32_t p = atomicAdd(&ccnt, 1u);
            if (p < 64u) cbuf[p] = MKKEY(s);
        }
    }
#undef MKKEY
    __syncthreads();
    const uint32_t n = ccnt < 64u ? ccnt : 64u;
    // wave 0: bitonic sort 64 via shfl (same network as proven sort_kernel)
    if (t < 64) {
        unsigned long long key = ((uint32_t)t < n) ? cbuf[t] : ~0ull;
#pragma unroll
        for (int k = 2; k <= 64; k <<= 1) {
            for (int j2 = k >> 1; j2 > 0; j2 >>= 1) {
                unsigned long long o = __shfl_xor(key, j2, 64);
                bool up = ((t & k) == 0);
                bool lower = ((t & j2) == 0);
                unsigned long long mn = key < o ? key : o;
                unsigned long long mx = key < o ? o : key;
                key = (up == lower) ? mn : mx;
            }
        }
        if (t < KNB) edges[(size_t)row * KNB + t] = (int)(key & 0xffffffffu);
    }
}

// ---------------- one smoothing step (all selected neighbors are valid) -------
__global__ void smooth_kernel(const float* __restrict__ zin,
                              float* __restrict__ zout,
                              const int* __restrict__ edges,
                              const int* __restrict__ C) {
    int t = blockIdx.x * blockDim.x + threadIdx.x;
    if (t >= TOT) return;
    float acc = 0.0f;
    if (C[t] > 0) {
        const int b = t >> 13;
        const int* e = edges + (size_t)t * KNB;
        const float* zb = zin + (size_t)b * NN;
#pragma unroll
        for (int k = 0; k < KNB; ++k) acc = __fadd_rn(acc, zb[e[k]]);
        acc = __fdiv_rn(acc, __fadd_rn(30.0f, 1e-5f));
    }
    zout[t] = acc;
}

// ---------------- z += priority; stable ascending argsort per batch ----------
__global__ __launch_bounds__(1024) void sort_kernel(const float* __restrict__ z,
                                                    const float* __restrict__ prio,
                                                    int* __restrict__ out) {
    __shared__ unsigned long long keys[NN];  // 64 KiB
    const int b = blockIdx.x;
    for (int i = threadIdx.x; i < NN; i += 1024) {
        float v = z[(size_t)b * NN + i] + prio[(size_t)b * NN + i];
        uint32_t u = __float_as_uint(v);
        u ^= (u >> 31) ? 0xFFFFFFFFu : 0x80000000u;  // monotonic float->uint
        keys[i] = ((unsigned long long)u << 32) | (unsigned)i;
    }
    __syncthreads();
    for (int k = 2; k <= NN; k <<= 1) {
        for (int j = k >> 1; j > 0; j >>= 1) {
            for (int i = threadIdx.x; i < NN; i += 1024) {
                int ixj = i ^ j;
                if (ixj > i) {
                    unsigned long long a = keys[i], c = keys[ixj];
                    bool up = ((i & k) == 0);
                    if ((a > c) == up) { keys[i] = c; keys[ixj] = a; }
                }
            }
            __syncthreads();
        }
    }
    for (int i = threadIdx.x; i < NN; i += 1024)
        out[(size_t)b * NN + i] = (int)(keys[i] & 0xffffffffu);
}

extern "C" void kernel_launch(void* const* d_in, const int* in_sizes, int n_in,
                              void* d_out, int out_size, void* d_ws, size_t ws_size,
                              hipStream_t stream) {
    const float* X = (const float*)d_in[0];    // [4,8192,3] f32
    const int* C = (const int*)d_in[1];        // [4,8192] int32
    const float* prio = (const float*)d_in[2]; // [4,8192] f32
    int* out = (int*)d_out;                    // [4,8192] i32

    float* z0 = (float*)d_ws;
    float* z1 = z0 + TOT;
    int* edges = (int*)(z1 + TOT);

    init_z_kernel<<<TOT / 256, 256, 0, stream>>>(z0);
    knn_kernel<<<TOT, 256, 0, stream>>>(X, C, edges);

    float* cur = z0;
    float* nxt = z1;
    for (int s = 0; s < 5; ++s) {
        smooth_kernel<<<TOT / 256, 256, 0, stream>>>(cur, nxt, edges, C);
        float* tmp = cur; cur = nxt; nxt = tmp;
    }
    sort_kernel<<<NB, 1024, 0, stream>>>(cur, prio, out);
}

// Round 11
// 531.509 us; speedup vs baseline: 4.8376x; 1.1483x over previous
//
#include <hip/hip_runtime.h>
#include <stdint.h>

#define NB 4
#define NN 8192
#define KNB 30
#define TOT (NB * NN)

// ---------------- threefry2x32 (JAX-exact, key = [0, 42]) ----------------
__device__ __forceinline__ uint32_t rotl32(uint32_t v, int r) {
    return (v << r) | (v >> (32 - r));
}

__device__ __forceinline__ void threefry(uint32_t x0, uint32_t x1,
                                         uint32_t& o0, uint32_t& o1) {
    const uint32_t ks0 = 0u, ks1 = 42u, ks2 = 0u ^ 42u ^ 0x1BD11BDAu;
    x0 += ks0; x1 += ks1;
#define RND(r) { x0 += x1; x1 = rotl32(x1, r); x1 ^= x0; }
    RND(13) RND(15) RND(26) RND(6)
    x0 += ks1; x1 += ks2 + 1u;
    RND(17) RND(29) RND(16) RND(24)
    x0 += ks2; x1 += ks0 + 2u;
    RND(13) RND(15) RND(26) RND(6)
    x0 += ks0; x1 += ks1 + 3u;
    RND(17) RND(29) RND(16) RND(24)
    x0 += ks1; x1 += ks2 + 4u;
    RND(13) RND(15) RND(26) RND(6)
    x0 += ks2; x1 += ks0 + 5u;
#undef RND
    o0 = x0; o1 = x1;
}

// jax_threefry_partitionable=True: bits[t] = o0^o1 of threefry(key, 0, t)
__global__ void init_z_kernel(float* __restrict__ z) {
    int t = blockIdx.x * blockDim.x + threadIdx.x;
    if (t >= TOT) return;
    uint32_t o0, o1;
    threefry(0u, (uint32_t)t, o0, o1);
    uint32_t bits = o0 ^ o1;
    z[t] = __uint_as_float((bits >> 9) | 0x3f800000u) - 1.0f;
}

// ---------------- SoA transpose: X[b][n][3] -> Xs[b][3][NN] ------------------
__global__ void transpose_kernel(const float* __restrict__ X,
                                 float* __restrict__ Xs) {
    int t = blockIdx.x * blockDim.x + threadIdx.x;
    if (t >= TOT) return;
    const int b = t >> 13, n = t & (NN - 1);
    const float* src = X + (size_t)b * NN * 3 + (size_t)n * 3;
    float* dst = Xs + (size_t)b * 3 * NN;
    dst[0 * NN + n] = src[0];
    dst[1 * NN + n] = src[1];
    dst[2 * NN + n] = src[2];
}

// ---------------- kNN via radix-select with early exit -----------------------
// Keys: (d2_bits << 32) | j. d2 >= 0 -> float bits monotonic as uint; keys
// unique (j); ascending (d2bits, j) == lax.top_k order incl. tie-break.
// Thread t owns j = g*1024 + t*4 + q (g<8, q<4), s = g*4+q. float4/int4 loads
// from SoA Xs; d2 ladder ops VERBATIM (bit-identical values).
// Histogram counts only keys with hb < bits(1e9): invalid/self keys (d2>=1e9)
// can never reach rank 30 (~4096 valid per row), and they were the 16-way
// same-address atomic cluster at L0 (7.3e7 conflict cycles in R9/R10).
__global__ __launch_bounds__(256) void knn_kernel(const float* __restrict__ Xs,
                                                  const float* __restrict__ X,
                                                  const int* __restrict__ C,
                                                  int* __restrict__ edges) {
    const int row = blockIdx.x;          // 0..TOT-1 (block per row)
    const int b = row >> 13;
    const int i = row & (NN - 1);
    const float* Xsb = Xs + (size_t)b * 3 * NN;
    const int* Cb = C + (size_t)b * NN;
    const float xi = X[(size_t)b * NN * 3 + i * 3 + 0];
    const float yi = X[(size_t)b * NN * 3 + i * 3 + 1];
    const float zi = X[(size_t)b * NN * 3 + i * 3 + 2];
    const int t = threadIdx.x;
    const uint32_t BIGBITS = __float_as_uint(1e9f);

    // d2 for j = g*1024 + t*4 + q, exact reference op order (values identical
    // to the R4-proven ladder; only the load source/ownership changed)
    float d[32];
#pragma unroll
    for (int g = 0; g < 8; ++g) {
        const int j0 = g * 1024 + t * 4;
        const float4 x4 = *(const float4*)(Xsb + 0 * NN + j0);
        const float4 y4 = *(const float4*)(Xsb + 1 * NN + j0);
        const float4 z4 = *(const float4*)(Xsb + 2 * NN + j0);
        const int4 c4 = *(const int4*)(Cb + j0);
#define D2(q, xx, yy, zz, cc)                                                  \
        {                                                                      \
            float dx = __fsub_rn(xi, (xx));                                    \
            float dy = __fsub_rn(yi, (yy));                                    \
            float dz = __fsub_rn(zi, (zz));                                    \
            float d2 = __fadd_rn(__fadd_rn(__fmul_rn(dx, dx),                  \
                                           __fmul_rn(dy, dy)),                 \
                                 __fmul_rn(dz, dz));                           \
            d2 = __fadd_rn(d2, ((cc) > 0) ? 0.0f : 1e9f);                      \
            d2 = __fadd_rn(d2, ((j0 + (q)) == i) ? 1e9f : 0.0f);               \
            d[g * 4 + (q)] = d2;                                               \
        }
        D2(0, x4.x, y4.x, z4.x, c4.x)
        D2(1, x4.y, y4.y, z4.y, c4.y)
        D2(2, x4.z, y4.z, z4.z, c4.z)
        D2(3, x4.w, y4.w, z4.w, c4.w)
#undef D2
    }

#define MKKEY(s) ((((unsigned long long)__float_as_uint(d[(s)])) << 32) | \
                  (unsigned)((((s) >> 2) * 1024) + t * 4 + ((s) & 3)))

    __shared__ uint32_t hist[16][257];   // 16 sub-hists, +1 pad breaks bank alias
    __shared__ uint32_t sel3[3];         // [0]=prefix, [1]=remaining rank, [2]=cB
    __shared__ unsigned long long cbuf[64];
    __shared__ uint32_t ccnt;

    const int sh = t >> 4;               // sub-histogram id (16 threads each)
    if (t == 0) { sel3[0] = 0u; sel3[1] = (uint32_t)KNB; sel3[2] = 0u; ccnt = 0u; }

    int exitShift = 0;                   // shift of the level we stopped at
    for (int L = 0; L < 4; ++L) {
        const int shift = 24 - 8 * L;
        const uint32_t pmask = (L == 0) ? 0u : (0xFFFFFFFFu << (32 - 8 * L));
        for (int q = 0; q < 16; ++q) hist[q][t] = 0u;
        __syncthreads();                 // also publishes sel3/ccnt init (L=0)
        const uint32_t pref = sel3[0];
#pragma unroll
        for (int s = 0; s < 32; ++s) {
            uint32_t hb = __float_as_uint(d[s]);
            if ((hb & pmask) == pref && hb < BIGBITS)
                atomicAdd(&hist[sh][(hb >> shift) & 255], 1u);
        }
        __syncthreads();
        uint32_t colsum = 0;
#pragma unroll
        for (int q = 0; q < 16; ++q) colsum += hist[q][t];
        hist[0][t] = colsum;
        __syncthreads();
        // wave 0: find bucket containing remaining rank r (1-indexed)
        if (t < 64) {
            uint32_t c0 = hist[0][4 * t + 0], c1 = hist[0][4 * t + 1];
            uint32_t c2 = hist[0][4 * t + 2], c3 = hist[0][4 * t + 3];
            uint32_t lsum = c0 + c1 + c2 + c3;
            uint32_t inc = lsum;
#pragma unroll
            for (int off = 1; off < 64; off <<= 1) {
                uint32_t o = __shfl_up(inc, off, 64);
                if (t >= off) inc += o;
            }
            uint32_t exc = inc - lsum;
            uint32_t r = sel3[1];
            if (exc < r && r <= inc) {   // exactly one lane brackets r
                uint32_t e = exc, bkt, cB;
                if (r <= e + c0)                { bkt = 4u * t + 0u; cB = c0; }
                else if (r <= e + c0 + c1)      { bkt = 4u * t + 1u; cB = c1; e += c0; }
                else if (r <= e + c0 + c1 + c2) { bkt = 4u * t + 2u; cB = c2; e += c0 + c1; }
                else                            { bkt = 4u * t + 3u; cB = c3; e += c0 + c1 + c2; }
                sel3[0] = pref | (bkt << shift);
                sel3[1] = r - e;         // rank within chosen bucket
                sel3[2] = cB;            // bucket population
            }
        }
        __syncthreads();
        // uniform early exit: collected set (below-prefix + bucket) fits cbuf
        if ((uint32_t)KNB - sel3[1] + sel3[2] <= 64u) { exitShift = shift; break; }
    }

    const uint32_t V = sel3[0] | ((exitShift > 0) ? ((1u << exitShift) - 1u) : 0u);
    // collect all keys with d2bits <= V (30 <= n <= 64 on early exit)
#pragma unroll
    for (int s = 0; s < 32; ++s) {
        uint32_t hb = __float_as_uint(d[s]);
        if (hb <= V) {
            uint32_t p = atomicAdd(&ccnt, 1u);
            if (p < 64u) cbuf[p] = MKKEY(s);
        }
    }
#undef MKKEY
    __syncthreads();
    const uint32_t n = ccnt < 64u ? ccnt : 64u;
    // wave 0: bitonic sort 64 via shfl (same network as proven sort_kernel)
    if (t < 64) {
        unsigned long long key = ((uint32_t)t < n) ? cbuf[t] : ~0ull;
#pragma unroll
        for (int k = 2; k <= 64; k <<= 1) {
            for (int j2 = k >> 1; j2 > 0; j2 >>= 1) {
                unsigned long long o = __shfl_xor(key, j2, 64);
                bool up = ((t & k) == 0);
                bool lower = ((t & j2) == 0);
                unsigned long long mn = key < o ? key : o;
                unsigned long long mx = key < o ? o : key;
                key = (up == lower) ? mn : mx;
            }
        }
        if (t < KNB) edges[(size_t)row * KNB + t] = (int)(key & 0xffffffffu);
    }
}

// ---------------- one smoothing step (all selected neighbors are valid) -------
__global__ void smooth_kernel(const float* __restrict__ zin,
                              float* __restrict__ zout,
                              const int* __restrict__ edges,
                              const int* __restrict__ C) {
    int t = blockIdx.x * blockDim.x + threadIdx.x;
    if (t >= TOT) return;
    float acc = 0.0f;
    if (C[t] > 0) {
        const int b = t >> 13;
        const int* e = edges + (size_t)t * KNB;
        const float* zb = zin + (size_t)b * NN;
#pragma unroll
        for (int k = 0; k < KNB; ++k) acc = __fadd_rn(acc, zb[e[k]]);
        acc = __fdiv_rn(acc, __fadd_rn(30.0f, 1e-5f));
    }
    zout[t] = acc;
}

// ---------------- z += priority; stable ascending argsort per batch ----------
__global__ __launch_bounds__(1024) void sort_kernel(const float* __restrict__ z,
                                                    const float* __restrict__ prio,
                                                    int* __restrict__ out) {
    __shared__ unsigned long long keys[NN];  // 64 KiB
    const int b = blockIdx.x;
    for (int i = threadIdx.x; i < NN; i += 1024) {
        float v = z[(size_t)b * NN + i] + prio[(size_t)b * NN + i];
        uint32_t u = __float_as_uint(v);
        u ^= (u >> 31) ? 0xFFFFFFFFu : 0x80000000u;  // monotonic float->uint
        keys[i] = ((unsigned long long)u << 32) | (unsigned)i;
    }
    __syncthreads();
    for (int k = 2; k <= NN; k <<= 1) {
        for (int j = k >> 1; j > 0; j >>= 1) {
            for (int i = threadIdx.x; i < NN; i += 1024) {
                int ixj = i ^ j;
                if (ixj > i) {
                    unsigned long long a = keys[i], c = keys[ixj];
                    bool up = ((i & k) == 0);
                    if ((a > c) == up) { keys[i] = c; keys[ixj] = a; }
                }
            }
            __syncthreads();
        }
    }
    for (int i = threadIdx.x; i < NN; i += 1024)
        out[(size_t)b * NN + i] = (int)(keys[i] & 0xffffffffu);
}

extern "C" void kernel_launch(void* const* d_in, const int* in_sizes, int n_in,
                              void* d_out, int out_size, void* d_ws, size_t ws_size,
                              hipStream_t stream) {
    const float* X = (const float*)d_in[0];    // [4,8192,3] f32
    const int* C = (const int*)d_in[1];        // [4,8192] int32
    const float* prio = (const float*)d_in[2]; // [4,8192] f32
    int* out = (int*)d_out;                    // [4,8192] i32

    float* z0 = (float*)d_ws;
    float* z1 = z0 + TOT;
    int* edges = (int*)(z1 + TOT);             // TOT*30 ints
    float* Xs = (float*)(edges + (size_t)TOT * KNB);  // [NB][3][NN]

    init_z_kernel<<<TOT / 256, 256, 0, stream>>>(z0);
    transpose_kernel<<<TOT / 256, 256, 0, stream>>>(X, Xs);
    knn_kernel<<<TOT, 256, 0, stream>>>(Xs, X, C, edges);

    float* cur = z0;
    float* nxt = z1;
    for (int s = 0; s < 5; ++s) {
        smooth_kernel<<<TOT / 256, 256, 0, stream>>>(cur, nxt, edges, C);
        float* tmp = cur; cur = nxt; nxt = tmp;
    }
    sort_kernel<<<NB, 1024, 0, stream>>>(cur, prio, out);
}